// Round 8
// baseline (66058.704 us; speedup 1.0000x reference)
//
#include <hip/hip_runtime.h>

#define SEQ 32768
#define ISZ 256
#define HSZ 512
#define OSZ 256
#define GWG 2            // two agents — minimal fabric participants
#define RTHREADS 512     // 8 waves per WG
#define SENT 0x7FAAAAAAu // NaN sentinel: h = tanh(finite) is never NaN

typedef _Float16 half2_t __attribute__((ext_vector_type(2)));

#if defined(__has_builtin)
#if __has_builtin(__builtin_amdgcn_fdot2)
#define HAVE_FDOT2 1
#endif
#endif

__device__ __forceinline__ float dot2f(half2_t a, half2_t b, float c) {
#ifdef HAVE_FDOT2
  return __builtin_amdgcn_fdot2(a, b, c, false);   // v_dot2_f32_f16
#else
  return fmaf((float)a.x, (float)b.x, fmaf((float)a.y, (float)b.y, c));
#endif
}
__device__ __forceinline__ half2_t bch2(unsigned u) {
  return __builtin_bit_cast(half2_t, u);
}

// ---------------------------------------------------------------------------
// Generic tiled GEMM:  C[M,N] = A[M,K] @ W[N,K]^T + bias[N]
// ---------------------------------------------------------------------------
__global__ __launch_bounds__(256) void gemm_bt_bias(
    const float* __restrict__ A, const float* __restrict__ W,
    const float* __restrict__ bias, float* __restrict__ C,
    int M, int N, int K)
{
  __shared__ float As[32][68];
  __shared__ float Bs[32][68];
  const int tx = threadIdx.x;
  const int tn = tx & 15, tm = tx >> 4;
  const int m0 = blockIdx.x * 64, n0 = blockIdx.y * 64;
  const int kl = tx & 31;
  const int rl = tx >> 5;
  float acc[4][4] = {};

  for (int kt = 0; kt < K; kt += 32) {
#pragma unroll
    for (int i = 0; i < 8; ++i) {
      int m = rl + i * 8;
      As[kl][m] = A[(size_t)(m0 + m) * K + kt + kl];
      Bs[kl][m] = W[(size_t)(n0 + m) * K + kt + kl];
    }
    __syncthreads();
#pragma unroll
    for (int k = 0; k < 32; ++k) {
      float a[4], b[4];
#pragma unroll
      for (int i = 0; i < 4; ++i) a[i] = As[k][tm * 4 + i];
#pragma unroll
      for (int j = 0; j < 4; ++j) b[j] = Bs[k][tn * 4 + j];
#pragma unroll
      for (int i = 0; i < 4; ++i)
#pragma unroll
        for (int j = 0; j < 4; ++j)
          acc[i][j] = fmaf(a[i], b[j], acc[i][j]);
    }
    __syncthreads();
  }
#pragma unroll
  for (int i = 0; i < 4; ++i) {
    int m = m0 + tm * 4 + i;
#pragma unroll
    for (int j = 0; j < 4; ++j) {
      int n = n0 + tn * 4 + j;
      C[(size_t)m * N + n] = acc[i][j] + bias[n];
    }
  }
}

// 2-deep pipelined sentinel poll (agent-coherent loads, L1+L2 bypass).
// Keeps two loads in flight, alternating vmcnt(1) waits -> detection lag
// ~1 RT instead of ~1.3-1.5 RT with serialized load+vmcnt(0) polling.
__device__ __forceinline__ float poll_sent(const float* p, unsigned sent) {
  float a, b;
  asm volatile(
      "s_waitcnt vmcnt(0)\n\t"
      "global_load_dword %0, %2, off sc0 sc1\n\t"
      "global_load_dword %1, %2, off sc0 sc1\n"
      "1:\n\t"
      "s_waitcnt vmcnt(1)\n\t"
      "v_cmp_eq_u32 vcc, %3, %0\n\t"
      "s_cbranch_vccz 3f\n\t"
      "global_load_dword %0, %2, off sc0 sc1\n\t"
      "s_waitcnt vmcnt(1)\n\t"
      "v_cmp_eq_u32 vcc, %3, %1\n\t"
      "s_cbranch_vccz 2f\n\t"
      "global_load_dword %1, %2, off sc0 sc1\n\t"
      "s_branch 1b\n"
      "2:\n\t"
      "v_mov_b32 %0, %1\n"
      "3:\n\t"
      "s_waitcnt vmcnt(0)"
      : "=&v"(a), "=&v"(b)
      : "v"(p), "v"(sent)
      : "memory", "vcc");
  return a;
}

__device__ __forceinline__ void wg_flag_set(int* f, int v) {
  __hip_atomic_store(f, v, __ATOMIC_RELEASE, __HIP_MEMORY_SCOPE_WORKGROUP);
}
__device__ __forceinline__ void wg_flag_wait(int* f, int v) {
  while (__hip_atomic_load(f, __ATOMIC_ACQUIRE, __HIP_MEMORY_SCOPE_WORKGROUP) < v) {}
}

// ---------------------------------------------------------------------------
// Persistent recurrence, ROUND-8: 2 agents, barrier-free, readlane+dot2.
//
// Evidence: r4 (8 WG) 3070 cy/step, r7 (2 WG, LDS-b128-broadcast dot) 3150
// cy/step — both = fabric publish->detect (~1400-1900 cy) PLUS ~1000-1500 cy
// of self-inflicted serialization (r4: s_barrier + wave0 reduce; r7: 256
// ds_read_b128 broadcasts/step ~12cy each on one LDS pipe + 2 barriers).
// This round removes the serialization:
//  - dot = v_readlane(SGPR broadcast) + v_dot2_f32_f16, h in VGPRs: 1
//    inst/col, no LDS-pipe pressure (only 2 ds_read_b32/wave/step).
//  - NO s_barrier in the loop: monotonic LDS flags (acquire/release,
//    workgroup scope) — each wave waits only on its true dependency; the
//    local-half dot + P-load hide entirely inside the peer fabric window.
//  - 2-deep pipelined poll (asm above).
// Thread (r=tid&255, kh=tid>>8) of WG g: weights Wh[256g+r][256kh..+256) as
// 128 half2 VGPRs. Remote waves (kh!=g) poll peer h, dot, +part, tanh,
// publish. Local waves (kh==g) dot own-half + fold in P -> part.
// ---------------------------------------------------------------------------
__global__ __launch_bounds__(RTHREADS, 2) void rnn_recur(
    const float* __restrict__ P,     // [SEQ][HSZ]  (Wx@x_t + bh)
    const float* __restrict__ Wh,    // [HSZ][HSZ]
    float* __restrict__ h_hist)      // [SEQ+1][HSZ]; row0=0, rows 1..=SENT
{
  const int g = blockIdx.x;          // 0 or 1
  const int tid = threadIdx.x;
  const int r = tid & 255;           // row within this WG's slice
  const int kh = tid >> 8;           // k-half this thread's weights cover
  const int rglob = (g << 8) + r;    // global row this thread produces
  const int lane = tid & 63;
  const int wave = tid >> 6;
  const int rwi = wave & 3;          // index within the 4-wave role group
  const bool is_remote = (kh != g);

  // ---- weights: Wh[rglob][256*kh .. +256) as 128 half2 (pinned) ----
  unsigned wreg[128];
  {
    const float2* wsrc = (const float2*)(Wh + (size_t)rglob * HSZ + (kh << 8));
#pragma unroll
    for (int j = 0; j < 128; ++j) {
      float2 wf = wsrc[j];
      half2_t hv; hv.x = (_Float16)wf.x; hv.y = (_Float16)wf.y;
      unsigned u = __builtin_bit_cast(unsigned, hv);
      asm("" : "+v"(u));
      wreg[j] = u;
    }
  }

  // LDS state. Flags are monotonic step counters (init 0, never reset).
  __shared__ _Float16 hown[2][256];  // own-half h (f16), buf = s&1 when written at step s
  __shared__ _Float16 hrem[2][256];  // peer-half h (f16), buf = (s-1)&1 at step s
  __shared__ float    part[2][256];  // local dot + P, buf = s&1
  __shared__ int      hflag[2][4];   // remote -> local: hown chunk ready
  __shared__ int      rflag[2][4];   // remote -> remote: hrem chunk ready
  __shared__ int      pflag[2][4];   // local -> remote: part chunk ready

  if (tid < 256) hown[0][tid] = (_Float16)0.f;   // h_0 = 0
  if (tid < 4) {
    hflag[0][tid] = 0; hflag[1][tid] = 0;
    rflag[0][tid] = 0; rflag[1][tid] = 0;
    pflag[0][tid] = 0; pflag[1][tid] = 0;
  }
  __syncthreads();   // prologue only — no barriers in the step loop

#define DOT128(hA, hB, res) {                                        \
    float a0 = 0.f, a1 = 0.f, a2 = 0.f, a3 = 0.f;                    \
    _Pragma("unroll")                                                \
    for (int p = 0; p < 64; ++p) {                                   \
      unsigned s0 = __builtin_amdgcn_readlane(hA, p);                \
      switch (p & 3) {                                               \
        case 0: a0 = dot2f(bch2(wreg[p]), bch2(s0), a0); break;      \
        case 1: a1 = dot2f(bch2(wreg[p]), bch2(s0), a1); break;      \
        case 2: a2 = dot2f(bch2(wreg[p]), bch2(s0), a2); break;      \
        default: a3 = dot2f(bch2(wreg[p]), bch2(s0), a3); break;     \
      }                                                              \
    }                                                                \
    _Pragma("unroll")                                                \
    for (int p = 0; p < 64; ++p) {                                   \
      unsigned s1 = __builtin_amdgcn_readlane(hB, p);                \
      switch (p & 3) {                                               \
        case 0: a0 = dot2f(bch2(wreg[64 + p]), bch2(s1), a0); break; \
        case 1: a1 = dot2f(bch2(wreg[64 + p]), bch2(s1), a1); break; \
        case 2: a2 = dot2f(bch2(wreg[64 + p]), bch2(s1), a2); break; \
        default: a3 = dot2f(bch2(wreg[64 + p]), bch2(s1), a3); break;\
      }                                                              \
    }                                                                \
    res = (a0 + a1) + (a2 + a3);                                     \
  }

  if (!is_remote) {
    // ---------------- LOCAL waves: own-half dot + P staging ----------------
    float pvCur = P[(size_t)0 * HSZ + rglob];          // P[0] for s=1
    for (int s = 1; s <= SEQ; ++s) {
      const int rb = (s - 1) & 1, wb = s & 1;
      // wait: hown[rb] = h_{s-1} complete (all 4 remote chunks)
      wg_flag_wait(&hflag[rb][0], s - 1);
      wg_flag_wait(&hflag[rb][1], s - 1);
      wg_flag_wait(&hflag[rb][2], s - 1);
      wg_flag_wait(&hflag[rb][3], s - 1);
      // prefetch P[s] for the next step (latency hidden behind the dot)
      float pvNext = P[(size_t)(s < SEQ ? s : SEQ - 1) * HSZ + rglob];
      // lane-distributed h pairs: lane l holds cols (2l,2l+1) / (128+2l,..)
      unsigned hA = ((const unsigned*)hown[rb])[lane];
      unsigned hB = ((const unsigned*)hown[rb])[64 + lane];
      float ldot;
      DOT128(hA, hB, ldot);
      part[wb][r] = ldot + pvCur;
      wg_flag_set(&pflag[wb][rwi], s);
      pvCur = pvNext;
    }
  } else {
    // ---------------- REMOTE waves: poll peer, dot, tanh, publish ----------
    const unsigned sentv = SENT;
    const int peerbase = ((1 - g) << 8) + (rwi << 6) + lane;
    for (int s = 1; s <= SEQ; ++s) {
      const int rb = (s - 1) & 1, wb = s & 1;
      // 1) poll my 64 floats of peer h_{s-1}
      float vh = poll_sent(h_hist + (size_t)(s - 1) * HSZ + peerbase, sentv);
      // 2) stage f16 into hrem and mark my chunk
      hrem[rb][(rwi << 6) + lane] = (_Float16)vh;
      wg_flag_set(&rflag[rb][rwi], s);
      // 3) wait for the other 3 chunks (usually already set)
      wg_flag_wait(&rflag[rb][0], s);
      wg_flag_wait(&rflag[rb][1], s);
      wg_flag_wait(&rflag[rb][2], s);
      wg_flag_wait(&rflag[rb][3], s);
      unsigned hA = ((const unsigned*)hrem[rb])[lane];
      unsigned hB = ((const unsigned*)hrem[rb])[64 + lane];
      float rdot;
      DOT128(hA, hB, rdot);
      // 4) add local partial (+P already folded in) — ready long ago
      wg_flag_wait(&pflag[wb][rwi], s);
      float xv = rdot + part[wb][r];
      // 5) tanh (fast form), publish fp32 (value IS the ready signal)
      xv = fminf(fmaxf(xv, -15.f), 15.f);
      float e = __expf(2.f * xv);
      float hn = 1.f - 2.f / (e + 1.f);
      __hip_atomic_store(&h_hist[(size_t)s * HSZ + rglob], hn,
                         __ATOMIC_RELAXED, __HIP_MEMORY_SCOPE_AGENT);
      // 6) stage own-half f16 for the local waves' next step
      hown[wb][r] = (_Float16)hn;
      wg_flag_set(&hflag[wb][rwi], s);
    }
  }
#undef DOT128
}

// ---------------------------------------------------------------------------
extern "C" void kernel_launch(void* const* d_in, const int* in_sizes, int n_in,
                              void* d_out, int out_size, void* d_ws, size_t ws_size,
                              hipStream_t stream) {
  const float* x  = (const float*)d_in[0];  // [SEQ][ISZ]
  const float* Wx = (const float*)d_in[1];  // [HSZ][ISZ]
  const float* Wh = (const float*)d_in[2];  // [HSZ][HSZ]
  const float* Wy = (const float*)d_in[3];  // [OSZ][HSZ]
  const float* bh = (const float*)d_in[4];  // [HSZ]
  const float* by = (const float*)d_in[5];  // [OSZ]
  float* out = (float*)d_out;               // [SEQ][OSZ]

  float* P      = (float*)d_ws;             // SEQ*HSZ      (64 MB)
  float* h_hist = P + (size_t)SEQ * HSZ;    // (SEQ+1)*HSZ  (64 MB)

  // Sentinel-fill h_hist rows (NaN bits), then zero row 0 (= h_0).
  hipMemsetD32Async((hipDeviceptr_t)h_hist, (int)SENT,
                    (size_t)(SEQ + 1) * HSZ, stream);
  hipMemsetAsync(h_hist, 0, HSZ * sizeof(float), stream);

  // Phase 1: P = x @ Wx^T + bh
  gemm_bt_bias<<<dim3(SEQ / 64, HSZ / 64), dim3(256), 0, stream>>>(
      x, Wx, bh, P, SEQ, HSZ, ISZ);

  // Phase 2: sequential recurrence (2 persistent WGs)
  rnn_recur<<<dim3(GWG), dim3(RTHREADS), 0, stream>>>(P, Wh, h_hist);

  // Phase 3: y = h_hist[1..] @ Wy^T + by
  gemm_bt_bias<<<dim3(SEQ / 64, OSZ / 64), dim3(256), 0, stream>>>(
      h_hist + HSZ, Wy, by, out, SEQ, OSZ, HSZ);
}

// Round 10
// 41189.490 us; speedup vs baseline: 1.6038x; 1.6038x over previous
//
#include <hip/hip_runtime.h>

#define SEQ 32768
#define ISZ 256
#define HSZ 512
#define OSZ 256
#define GWG 8            // 8 WGs (64 rows each) — r4-proven topology
#define RTHREADS 512     // 8 waves per WG
#define SENT 0x7FAAAAAAu // NaN sentinel: h = tanh(finite) is never NaN

typedef _Float16 half2_t __attribute__((ext_vector_type(2)));

#if defined(__has_builtin)
#if __has_builtin(__builtin_amdgcn_fdot2)
#define HAVE_FDOT2 1
#endif
#endif

__device__ __forceinline__ float dot2f(half2_t a, half2_t b, float c) {
#ifdef HAVE_FDOT2
  return __builtin_amdgcn_fdot2(a, b, c, false);   // v_dot2_f32_f16
#else
  return fmaf((float)a.x, (float)b.x, fmaf((float)a.y, (float)b.y, c));
#endif
}
__device__ __forceinline__ half2_t bch2(unsigned u) {
  return __builtin_bit_cast(half2_t, u);
}
// f32 pair -> packed f16x2 bits (v_cvt_pkrtz_f16_f32). The builtin returns
// __fp16x2, which isn't implicitly convertible to half2_t — bit_cast it.
__device__ __forceinline__ unsigned pkrtz_u(float x, float y) {
  return __builtin_bit_cast(unsigned, __builtin_amdgcn_cvt_pkrtz(x, y));
}

// ---------------------------------------------------------------------------
// Generic tiled GEMM:  C[M,N] = A[M,K] @ W[N,K]^T + bias[N]
// ---------------------------------------------------------------------------
__global__ __launch_bounds__(256) void gemm_bt_bias(
    const float* __restrict__ A, const float* __restrict__ W,
    const float* __restrict__ bias, float* __restrict__ C,
    int M, int N, int K)
{
  __shared__ float As[32][68];
  __shared__ float Bs[32][68];
  const int tx = threadIdx.x;
  const int tn = tx & 15, tm = tx >> 4;
  const int m0 = blockIdx.x * 64, n0 = blockIdx.y * 64;
  const int kl = tx & 31;
  const int rl = tx >> 5;
  float acc[4][4] = {};

  for (int kt = 0; kt < K; kt += 32) {
#pragma unroll
    for (int i = 0; i < 8; ++i) {
      int m = rl + i * 8;
      As[kl][m] = A[(size_t)(m0 + m) * K + kt + kl];
      Bs[kl][m] = W[(size_t)(n0 + m) * K + kt + kl];
    }
    __syncthreads();
#pragma unroll
    for (int k = 0; k < 32; ++k) {
      float a[4], b[4];
#pragma unroll
      for (int i = 0; i < 4; ++i) a[i] = As[k][tm * 4 + i];
#pragma unroll
      for (int j = 0; j < 4; ++j) b[j] = Bs[k][tn * 4 + j];
#pragma unroll
      for (int i = 0; i < 4; ++i)
#pragma unroll
        for (int j = 0; j < 4; ++j)
          acc[i][j] = fmaf(a[i], b[j], acc[i][j]);
    }
    __syncthreads();
  }
#pragma unroll
  for (int i = 0; i < 4; ++i) {
    int m = m0 + tm * 4 + i;
#pragma unroll
    for (int j = 0; j < 4; ++j) {
      int n = n0 + tn * 4 + j;
      C[(size_t)m * N + n] = acc[i][j] + bias[n];
    }
  }
}

// 2-deep pipelined sentinel poll (r8-proven correct): two loads in flight,
// alternating vmcnt(1) waits -> detection lag ~1 RT.
__device__ __forceinline__ float poll_sent(const float* p, unsigned sent) {
  float a, b;
  asm volatile(
      "s_waitcnt vmcnt(0)\n\t"
      "global_load_dword %0, %2, off sc0 sc1\n\t"
      "global_load_dword %1, %2, off sc0 sc1\n"
      "1:\n\t"
      "s_waitcnt vmcnt(1)\n\t"
      "v_cmp_eq_u32 vcc, %3, %0\n\t"
      "s_cbranch_vccz 3f\n\t"
      "global_load_dword %0, %2, off sc0 sc1\n\t"
      "s_waitcnt vmcnt(1)\n\t"
      "v_cmp_eq_u32 vcc, %3, %1\n\t"
      "s_cbranch_vccz 2f\n\t"
      "global_load_dword %1, %2, off sc0 sc1\n\t"
      "s_branch 1b\n"
      "2:\n\t"
      "v_mov_b32 %0, %1\n"
      "3:\n\t"
      "s_waitcnt vmcnt(0)"
      : "=&v"(a), "=&v"(b)
      : "v"(p), "v"(sent)
      : "memory", "vcc");
  return a;
}

// ---------------------------------------------------------------------------
// Persistent recurrence, ROUND-9: r4 topology + tiny f16 weights + no barrier.
//
// Evidence chain: r4 (fp32 fma dot, barrier+wave0 reduce) = 3070 cy/step.
// r8 (2 WG, 128-VGPR weights) regressed: allocator refused residency a 4th
// time (VGPR=104<128) and the 256-VALU dot serialized with the fabric RT.
// Fix: make the weight footprint trivially small (32 half2 VGPRs = 64 f16
// cols/lane) so residency is unavoidable, the dot tiny (32 readlane + 32
// v_dot2_f32_f16 ~ 70 VALU/wave), and the barrier gone (monotonic LDS
// flags; waves 1-7 flag their partial and immediately re-enter their poll,
// which then absorbs wave0's reduce+publish+fabric window).
// WG g owns rows [64g,64g+64); wave w consumes h chunk w = WG w's publish
// (single flag-free sentinel poll on own 64 floats — r4-proven protocol).
// ---------------------------------------------------------------------------
__global__ __launch_bounds__(RTHREADS, 2) void rnn_recur(
    const float* __restrict__ P,     // [SEQ][HSZ]  (Wx@x_t + bh)
    const float* __restrict__ Wh,    // [HSZ][HSZ]
    float* __restrict__ h_hist)      // [SEQ+1][HSZ]; row0=0, rows 1..=SENT
{
  const int g = blockIdx.x;
  const int tid = threadIdx.x;
  const int w = tid >> 6;          // wave index = consumed h chunk
  const int l = tid & 63;          // lane = row within WG slice
  const int g64 = g << 6;
  const int row = g64 + l;
  const int kbase = w << 6;

  // Lane's 64 weights, f16-packed: 32 half2 = 32 VGPRs. Small enough that
  // the allocator has no reason to spill or rematerialize.
  unsigned wreg[32];
  {
    const float2* ws = (const float2*)(Wh + (size_t)row * HSZ + kbase);
#pragma unroll
    for (int j = 0; j < 32; ++j) {
      float2 f = ws[j];
      unsigned u = pkrtz_u(f.x, f.y);
      asm("" : "+v"(u));
      wreg[j] = u;
    }
  }

  __shared__ float part[2][8][64];   // double-buffered partials
  __shared__ int   wflag[8];         // monotonic per-wave step counters
  if (tid < 8) wflag[tid] = 0;
  __syncthreads();                   // prologue only

  float pv = (w == 0) ? P[(size_t)0 * HSZ + g64 + l] : 0.f;   // P[0]

  for (int t = 0; t < SEQ; ++t) {
    const int buf = t & 1;

    // 1) Poll own h chunk (lane l -> element l). Row 0 pre-zeroed.
    float vh = poll_sent(h_hist + (size_t)t * HSZ + kbase + l, SENT);

    // 2) Pack h to f16 pairs: even lane 2j ends up with (h[2j], h[2j+1]).
    float vn = __shfl_xor(vh, 1);
    unsigned hpu = pkrtz_u(vh, vn);

    // 3) Dot: 32 readlane-broadcasts + 32 dot2, 4 accumulator chains.
    float a0 = 0.f, a1 = 0.f, a2 = 0.f, a3 = 0.f;
#pragma unroll
    for (int j = 0; j < 8; ++j) {
      a0 = dot2f(bch2(wreg[4 * j + 0]),
                 bch2(__builtin_amdgcn_readlane(hpu, 8 * j + 0)), a0);
      a1 = dot2f(bch2(wreg[4 * j + 1]),
                 bch2(__builtin_amdgcn_readlane(hpu, 8 * j + 2)), a1);
      a2 = dot2f(bch2(wreg[4 * j + 2]),
                 bch2(__builtin_amdgcn_readlane(hpu, 8 * j + 4)), a2);
      a3 = dot2f(bch2(wreg[4 * j + 3]),
                 bch2(__builtin_amdgcn_readlane(hpu, 8 * j + 6)), a3);
    }
    part[buf][w][l] = (a0 + a1) + (a2 + a3);

    // 4) Release-flag my partial (monotonic; no reset, no barrier).
    if (l == 0)
      __hip_atomic_store(&wflag[w], t + 1, __ATOMIC_RELEASE,
                         __HIP_MEMORY_SCOPE_WORKGROUP);
    // Waves 1-7: done — loop back to the next poll immediately; that poll
    // runs concurrently with wave0's reduce+publish+fabric latency.

    if (w == 0) {
      // 5) Wait all 8 partials (lane-parallel spin over the 8 flags).
      int fv;
      do {
        fv = __hip_atomic_load(&wflag[l & 7], __ATOMIC_ACQUIRE,
                               __HIP_MEMORY_SCOPE_WORKGROUP);
      } while (__any((int)(fv < t + 1)));
      // 6) Reduce 8 partials (conflict-free column reads) + P + tanh.
      float s = 0.f;
#pragma unroll
      for (int q = 0; q < 8; ++q) s += part[buf][q][l];
      float xv = s + pv;
      // prefetch next P (has a full fabric RT to arrive)
      pv = P[(size_t)(t + 1 < SEQ ? t + 1 : SEQ - 1) * HSZ + g64 + l];
      xv = fminf(fmaxf(xv, -15.f), 15.f);
      float e = __expf(2.f * xv);
      float hn = 1.f - 2.f / (e + 1.f);
      // 7) Publish: value IS the ready signal (r4-proven protocol).
      __hip_atomic_store(&h_hist[(size_t)(t + 1) * HSZ + g64 + l], hn,
                         __ATOMIC_RELAXED, __HIP_MEMORY_SCOPE_AGENT);
    }
  }
}

// ---------------------------------------------------------------------------
extern "C" void kernel_launch(void* const* d_in, const int* in_sizes, int n_in,
                              void* d_out, int out_size, void* d_ws, size_t ws_size,
                              hipStream_t stream) {
  const float* x  = (const float*)d_in[0];  // [SEQ][ISZ]
  const float* Wx = (const float*)d_in[1];  // [HSZ][ISZ]
  const float* Wh = (const float*)d_in[2];  // [HSZ][HSZ]
  const float* Wy = (const float*)d_in[3];  // [OSZ][HSZ]
  const float* bh = (const float*)d_in[4];  // [HSZ]
  const float* by = (const float*)d_in[5];  // [OSZ]
  float* out = (float*)d_out;               // [SEQ][OSZ]

  float* P      = (float*)d_ws;             // SEQ*HSZ      (64 MB)
  float* h_hist = P + (size_t)SEQ * HSZ;    // (SEQ+1)*HSZ  (64 MB)

  // Sentinel-fill h_hist rows (NaN bits), then zero row 0 (= h_0).
  (void)hipMemsetD32Async((hipDeviceptr_t)h_hist, (int)SENT,
                          (size_t)(SEQ + 1) * HSZ, stream);
  (void)hipMemsetAsync(h_hist, 0, HSZ * sizeof(float), stream);

  // Phase 1: P = x @ Wx^T + bh
  gemm_bt_bias<<<dim3(SEQ / 64, HSZ / 64), dim3(256), 0, stream>>>(
      x, Wx, bh, P, SEQ, HSZ, ISZ);

  // Phase 2: sequential recurrence (8 persistent WGs)
  rnn_recur<<<dim3(GWG), dim3(RTHREADS), 0, stream>>>(P, Wh, h_hist);

  // Phase 3: y = h_hist[1..] @ Wy^T + by
  gemm_bt_bias<<<dim3(SEQ / 64, OSZ / 64), dim3(256), 0, stream>>>(
      h_hist + HSZ, Wy, by, out, SEQ, OSZ, HSZ);
}